// Round 5
// baseline (227.383 us; speedup 1.0000x reference)
//
#include <hip/hip_runtime.h>

static constexpr int DM = 1024;   // d_model
static constexpr int NH = 16;     // heads
static constexpr int DK = 64;     // head dim
static constexpr int S  = 2048;   // seq len
static constexpr int B  = 2;      // batch
static constexpr float LOG2E = 1.4426950408889634f;
static constexpr float FMAX  = 11.0f;   // fixed softmax shift (exp2 domain)

typedef _Float16 f16;
typedef _Float16 f16x8 __attribute__((ext_vector_type(8)));
typedef _Float16 f16x4 __attribute__((ext_vector_type(4)));
typedef float    f32x4 __attribute__((ext_vector_type(4)));

static constexpr size_t NX = (size_t)B * S * DM;   // 4,194,304
static constexpr size_t NW = (size_t)DM * DM;      // 1,048,576

// async global->LDS 16B DMA: dest = ldsbase + lane*16
__device__ __forceinline__ void gload16(f16* lds, const f16* g) {
    __builtin_amdgcn_global_load_lds(
        (__attribute__((address_space(1))) void*)g,
        (__attribute__((address_space(3))) void*)lds,
        16, 0, 0);
}

// ---------------------------------------------------------------------------
// fp32 -> f16 conversion for x and the four weight matrices (one launch).
// ---------------------------------------------------------------------------
__global__ __launch_bounds__(256) void cvt_f16(const float* __restrict__ x,
                                               const float* __restrict__ wq,
                                               const float* __restrict__ wk,
                                               const float* __restrict__ wv,
                                               const float* __restrict__ wo,
                                               f16* __restrict__ xh,
                                               f16* __restrict__ wqh,
                                               f16* __restrict__ wkh,
                                               f16* __restrict__ wvh,
                                               f16* __restrict__ woh)
{
    const size_t base = ((size_t)blockIdx.x * 256 + threadIdx.x) * 8;
    const float* src; f16* dst; size_t off;
    if (base < NX) { src = x; dst = xh; off = base; }
    else {
        const size_t rem = base - NX;
        const int seg = (int)(rem >> 20);
        off = rem & (NW - 1);
        src = seg == 0 ? wq : (seg == 1 ? wk : (seg == 2 ? wv : wo));
        dst = seg == 0 ? wqh : (seg == 1 ? wkh : (seg == 2 ? wvh : woh));
    }
    float4 a = *(const float4*)&src[off];
    float4 b = *(const float4*)&src[off + 4];
    f16x8 h = { (f16)a.x, (f16)a.y, (f16)a.z, (f16)a.w,
                (f16)b.x, (f16)b.y, (f16)b.z, (f16)b.w };
    *(f16x8*)&dst[off] = h;
}

// ---------------------------------------------------------------------------
// f16 MFMA GEMM, m97-style staging: global_load_lds width-16 DMA, XOR-swizzled
// source addressing (chunk c of row r -> slot r*8 + (c^(r&7))), no LDS pad.
// 128x128 tile, BK=64, 256 threads = 4 waves, wave-tile 64x64.
// MODE 0: fused QKV (grid.x=24, wsel=blockIdx.x>>3) -> f16 scatter (B,H,S,DK).
// MODE 1: out-proj (grid.x=8) -> fp32 row-major.
// ---------------------------------------------------------------------------
template<int MODE>
__global__ __launch_bounds__(256, 4) void gemm_h(const f16* __restrict__ A,
                                                 const f16* __restrict__ W0,
                                                 const f16* __restrict__ W1,
                                                 const f16* __restrict__ W2,
                                                 const float* __restrict__ b0,
                                                 const float* __restrict__ b1,
                                                 const float* __restrict__ b2,
                                                 void* __restrict__ o0,
                                                 void* __restrict__ o1,
                                                 void* __restrict__ o2)
{
    __shared__ f16 As[128 * 64];   // slot layout: row*64 + (c^(r&7))*8 halves
    __shared__ f16 Bs[128 * 64];

    const int t    = threadIdx.x;
    const int w    = t >> 6;
    const int lane = t & 63;
    const int tx   = lane & 15;
    const int quad = lane >> 4;
    const int wm   = w >> 1;
    const int wn   = w & 1;
    const int m0   = blockIdx.y * 128;

    const f16* W; const float* bias; f16* outh = nullptr; float* outf = nullptr;
    float scale; int n0;
    if (MODE == 0) {
        const int wsel = blockIdx.x >> 3;
        n0   = (blockIdx.x & 7) * 128;
        W    = wsel == 0 ? W0 : (wsel == 1 ? W1 : W2);
        bias = wsel == 0 ? b0 : (wsel == 1 ? b1 : b2);
        outh = (f16*)(wsel == 0 ? o0 : (wsel == 1 ? o1 : o2));
        scale = wsel == 0 ? LOG2E * 0.125f : 1.0f;
    } else {
        n0 = blockIdx.x * 128;
        W = W0; bias = b0; outf = (float*)o0; scale = 1.0f;
    }

    // DMA source addressing: wave w stages rows [w*32, w*32+32) of As and Bs.
    // Lane l, issue i: row = w*32 + i*8 + (l>>3); fetched chunk = (l&7)^(l>>3)
    // (so that slot chunk' = l&7 holds chunk (l&7)^(row&7); row&7 == l>>3).
    const int lrow = lane >> 3;                 // 0..7
    const int lchk = (lane & 7) ^ lrow;         // swizzled source chunk
    const f16* Ag = A + (size_t)(m0 + w*32 + lrow) * DM + lchk * 8;
    const f16* Bg = W + (size_t)(n0 + w*32 + lrow) * DM + lchk * 8;
    f16* Abase = &As[(w*32) * 64];              // + i*8 rows = i*512 halves
    f16* Bbase = &Bs[(w*32) * 64];

    f32x4 acc[4][4];
#pragma unroll
    for (int mt = 0; mt < 4; ++mt)
#pragma unroll
        for (int nt = 0; nt < 4; ++nt) acc[mt][nt] = (f32x4){0.f, 0.f, 0.f, 0.f};

    for (int k0 = 0; k0 < DM; k0 += 64) {
        __syncthreads();   // previous compute done before overwrite
#pragma unroll
        for (int i = 0; i < 4; ++i) {
            gload16(Abase + i*512, Ag + k0 + (size_t)(i*8) * DM);
            gload16(Bbase + i*512, Bg + k0 + (size_t)(i*8) * DM);
        }
        __syncthreads();   // drains vmcnt (compiler inserts) -> tiles ready

        f16x8 af[4][2];
#pragma unroll
        for (int mt = 0; mt < 4; ++mt)
#pragma unroll
            for (int ks = 0; ks < 2; ++ks)
                af[mt][ks] = *(const f16x8*)&As[(wm*64 + mt*16 + tx)*64
                                               + (((ks*4 + quad) ^ (tx & 7)) * 8)];
#pragma unroll
        for (int nt = 0; nt < 4; ++nt) {
#pragma unroll
            for (int ks = 0; ks < 2; ++ks) {
                f16x8 bf = *(const f16x8*)&Bs[(wn*64 + nt*16 + tx)*64
                                              + (((ks*4 + quad) ^ (tx & 7)) * 8)];
#pragma unroll
                for (int mt = 0; mt < 4; ++mt)
                    acc[mt][nt] = __builtin_amdgcn_mfma_f32_16x16x32_f16(af[mt][ks], bf, acc[mt][nt], 0, 0, 0);
            }
        }
    }

    // epilogue
#pragma unroll
    for (int nt = 0; nt < 4; ++nt) {
        const int n = n0 + wn*64 + nt*16 + tx;
        const float bn = bias[n];
#pragma unroll
        for (int mt = 0; mt < 4; ++mt)
#pragma unroll
            for (int r = 0; r < 4; ++r) {
                const int m = m0 + wm*64 + mt*16 + quad*4 + r;
                const float v = (acc[mt][nt][r] + bn) * scale;
                if (MODE == 0) {
                    const int bi = m >> 11;
                    const int ss = m & (S - 1);
                    const int h  = n >> 6;
                    const int dk = n & (DK - 1);
                    outh[((size_t)((bi*NH + h)*S + ss))*DK + dk] = (f16)v;
                } else {
                    outf[(size_t)m * DM + n] = v;
                }
            }
    }
}

// ---------------------------------------------------------------------------
// Flash attention v3 (unchanged from round 4): S^T trick + fixed-max softmax
// + 2-way seq split.
// ---------------------------------------------------------------------------
__global__ __launch_bounds__(256, 4) void attn_v3(const f16* __restrict__ Q,
                                                  const f16* __restrict__ K,
                                                  const f16* __restrict__ V,
                                                  const float* __restrict__ relb,
                                                  float* __restrict__ On,
                                                  float* __restrict__ lp)
{
    __shared__ f16 Ks[64*72];
    __shared__ f16 Vt[64*72];    // quad-grouped V^T: addr(d,s)=d*72+g(s)
    __shared__ float rb2[257];

    const int t    = threadIdx.x;
    const int w    = t >> 6;
    const int lane = t & 63;
    const int tx   = lane & 15;
    const int quad = lane >> 4;
    const int qt   = blockIdx.x >> 1;
    const int sp   = blockIdx.x & 1;
    const int h    = blockIdx.y;
    const int b    = blockIdx.z;
    const int q0   = qt * 128;

    const f16* Qb = Q + (size_t)((b*NH + h) * S) * DK;
    const f16* Kb = K + (size_t)((b*NH + h) * S) * DK;
    const f16* Vb = V + (size_t)((b*NH + h) * S) * DK;

    for (int i = t; i < 257; i += 256) rb2[i] = relb[h*257 + i] * LOG2E - FMAX;

    const int qrow = q0 + w*32 + tx;
    f16x8 qf[2][2];
#pragma unroll
    for (int qb = 0; qb < 2; ++qb)
#pragma unroll
        for (int ks = 0; ks < 2; ++ks)
            qf[qb][ks] = *(const f16x8*)(Qb + (size_t)(qrow + qb*16)*DK + ks*32 + quad*8);

    f32x4 oT[4][2];
    float lsum[2] = {0.f, 0.f};
#pragma unroll
    for (int d = 0; d < 4; ++d)
#pragma unroll
        for (int qb = 0; qb < 2; ++qb) oT[d][qb] = (f32x4){0.f, 0.f, 0.f, 0.f};

    const int kt0 = sp * (S/128);
    for (int kt = kt0; kt < kt0 + S/128; ++kt) {
        const int k0 = kt * 64;

        const int seq = t & 63, d0k = (t >> 6) * 16;
        f16x8 kr0 = *(const f16x8*)(Kb + (size_t)(k0 + seq)*DK + d0k);
        f16x8 kr1 = *(const f16x8*)(Kb + (size_t)(k0 + seq)*DK + d0k + 8);
        const int s2 = (t & 31) * 2, d0v = (t >> 5) * 8;
        f16x8 vr0 = *(const f16x8*)(Vb + (size_t)(k0 + s2    )*DK + d0v);
        f16x8 vr1 = *(const f16x8*)(Vb + (size_t)(k0 + s2 + 1)*DK + d0v);

        __syncthreads();
        *(f16x8*)&Ks[seq*72 + d0k    ] = kr0;
        *(f16x8*)&Ks[seq*72 + d0k + 8] = kr1;
        {   // V^T quad-grouped: g(s) = ((s>>2)&3)*16 + (s>>4)*4 + (s&3)
            const int g = ((s2 >> 2) & 3)*16 + (s2 >> 4)*4 + (s2 & 3);
            const unsigned short* u0 = (const unsigned short*)&vr0;
            const unsigned short* u1 = (const unsigned short*)&vr1;
#pragma unroll
            for (int j = 0; j < 8; ++j) {
                unsigned int pw = (unsigned int)u0[j] | ((unsigned int)u1[j] << 16);
                *(unsigned int*)&Vt[(d0v + j)*72 + g] = pw;
            }
        }
        __syncthreads();

        const bool farlo = (k0 - q0) >= 256;
        const bool farhi = (q0 - k0) >= 192;
        const float bconst = farlo ? rb2[0] : rb2[256];
        const int relbase = (q0 + w*32 + tx) - (k0 + quad*4);

        f16x4 pf[4][2];
#pragma unroll
        for (int sb = 0; sb < 4; ++sb) {
            f32x4 sT[2] = {(f32x4){0.f,0.f,0.f,0.f}, (f32x4){0.f,0.f,0.f,0.f}};
#pragma unroll
            for (int ks = 0; ks < 2; ++ks) {
                f16x8 kf = *(const f16x8*)&Ks[(sb*16 + tx)*72 + ks*32 + quad*8];
#pragma unroll
                for (int qb = 0; qb < 2; ++qb)
                    sT[qb] = __builtin_amdgcn_mfma_f32_16x16x32_f16(kf, qf[qb][ks], sT[qb], 0, 0, 0);
            }
            if (farlo | farhi) {
#pragma unroll
                for (int qb = 0; qb < 2; ++qb)
#pragma unroll
                    for (int r = 0; r < 4; ++r) {
                        const float p = exp2f(sT[qb][r] + bconst);
                        lsum[qb] += p;
                        pf[sb][qb][r] = (f16)p;
                    }
            } else {
#pragma unroll
                for (int qb = 0; qb < 2; ++qb)
#pragma unroll
                    for (int r = 0; r < 4; ++r) {
                        int rel = relbase + qb*16 - sb*16 - r;
                        rel = rel < -128 ? -128 : (rel > 128 ? 128 : rel);
                        const float p = exp2f(sT[qb][r] + rb2[rel + 128]);
                        lsum[qb] += p;
                        pf[sb][qb][r] = (f16)p;
                    }
            }
        }

#pragma unroll
        for (int d = 0; d < 4; ++d) {
#pragma unroll
            for (int sp2 = 0; sp2 < 2; ++sp2) {
                f16x8 vv = *(const f16x8*)&Vt[(d*16 + tx)*72 + quad*16 + sp2*8];
                f16x4 vlo = __builtin_shufflevector(vv, vv, 0, 1, 2, 3);
                f16x4 vhi = __builtin_shufflevector(vv, vv, 4, 5, 6, 7);
#pragma unroll
                for (int qb = 0; qb < 2; ++qb) {
                    oT[d][qb] = __builtin_amdgcn_mfma_f32_16x16x16f16(vlo, pf[sp2*2    ][qb], oT[d][qb], 0, 0, 0);
                    oT[d][qb] = __builtin_amdgcn_mfma_f32_16x16x16f16(vhi, pf[sp2*2 + 1][qb], oT[d][qb], 0, 0, 0);
                }
            }
        }
    }

#pragma unroll
    for (int qb = 0; qb < 2; ++qb) {
        float l = lsum[qb];
        l += __shfl_xor(l, 16);
        l += __shfl_xor(l, 32);
        const int q = q0 + w*32 + qb*16 + tx;
        if (quad == 0)
            lp[(((size_t)sp*B + b)*NH + h)*S + q] = l;
#pragma unroll
        for (int d = 0; d < 4; ++d)
            *(f32x4*)&On[(size_t)sp*NX + ((size_t)(b*S + q))*DM + h*DK + d*16 + quad*4] = oT[d][qb];
    }
}

// ---------------------------------------------------------------------------
// Combine the two seq-splits: AOh = (On0 + On1) / (l0 + l1), f16 output.
// ---------------------------------------------------------------------------
__global__ __launch_bounds__(256) void combine(const float* __restrict__ On,
                                               const float* __restrict__ lp,
                                               f16* __restrict__ AOh)
{
    const size_t i8 = ((size_t)blockIdx.x * 256 + threadIdx.x) * 8;
    const int token = (int)(i8 >> 10);
    const int c     = (int)(i8 & (DM - 1));
    const int b     = token >> 11;
    const int st    = token & (S - 1);
    const int h     = c >> 6;
    const float l = lp[((size_t)b*NH + h)*S + st]
                  + lp[(((size_t)B + b)*NH + h)*S + st];
    const float inv = 1.0f / l;
    float4 a0 = *(const float4*)&On[i8];
    float4 a1 = *(const float4*)&On[i8 + 4];
    float4 b0 = *(const float4*)&On[NX + i8];
    float4 b1 = *(const float4*)&On[NX + i8 + 4];
    f16x8 o = { (f16)((a0.x + b0.x) * inv), (f16)((a0.y + b0.y) * inv),
                (f16)((a0.z + b0.z) * inv), (f16)((a0.w + b0.w) * inv),
                (f16)((a1.x + b1.x) * inv), (f16)((a1.y + b1.y) * inv),
                (f16)((a1.z + b1.z) * inv), (f16)((a1.w + b1.w) * inv) };
    *(f16x8*)&AOh[i8] = o;
}

// ---------------------------------------------------------------------------
extern "C" void kernel_launch(void* const* d_in, const int* in_sizes, int n_in,
                              void* d_out, int out_size, void* d_ws, size_t ws_size,
                              hipStream_t stream)
{
    const float* x    = (const float*)d_in[0];
    const float* Wq   = (const float*)d_in[1];
    const float* bq   = (const float*)d_in[2];
    const float* Wk   = (const float*)d_in[3];
    const float* bk   = (const float*)d_in[4];
    const float* Wv   = (const float*)d_in[5];
    const float* bv   = (const float*)d_in[6];
    const float* Wo   = (const float*)d_in[7];
    const float* bo   = (const float*)d_in[8];
    const float* relb = (const float*)d_in[9];

    f16* Xh  = (f16*)d_ws;
    f16* Wqh = Xh  + NX;
    f16* Wkh = Wqh + NW;
    f16* Wvh = Wkh + NW;
    f16* Woh = Wvh + NW;
    f16* Qh  = Woh + NW;
    f16* Kh  = Qh  + NX;
    f16* Vh  = Kh  + NX;
    f16* AOh = Vh  + NX;
    float* On = (float*)(AOh + NX);       // 2*NX floats
    float* lpart = On + 2*NX;             // 2*B*NH*S floats

    cvt_f16<<<(NX + 4*NW) / (256*8), 256, 0, stream>>>(x, Wq, Wk, Wv, Wo,
                                                       Xh, Wqh, Wkh, Wvh, Woh);
    gemm_h<0><<<dim3(24, 32), 256, 0, stream>>>(Xh, Wqh, Wkh, Wvh,
                                                bq, bk, bv, Qh, Kh, Vh);
    attn_v3<<<dim3((S/128)*2, NH, B), 256, 0, stream>>>(Qh, Kh, Vh, relb, On, lpart);
    combine<<<NX / (256*8), 256, 0, stream>>>(On, lpart, AOh);
    gemm_h<1><<<dim3(8, 32), 256, 0, stream>>>(AOh, Woh, nullptr, nullptr,
                                               bo, nullptr, nullptr,
                                               d_out, nullptr, nullptr);
}

// Round 6
// 221.189 us; speedup vs baseline: 1.0280x; 1.0280x over previous
//
#include <hip/hip_runtime.h>

static constexpr int DM = 1024;   // d_model
static constexpr int NH = 16;     // heads
static constexpr int DK = 64;     // head dim
static constexpr int S  = 2048;   // seq len
static constexpr int B  = 2;      // batch
static constexpr float LOG2E = 1.4426950408889634f;
static constexpr float FMAX  = 11.0f;   // fixed softmax shift (exp2 domain)
static constexpr int NSPLIT = 4;        // k-range splits in attention

typedef _Float16 f16;
typedef _Float16 f16x8 __attribute__((ext_vector_type(8)));
typedef _Float16 f16x4 __attribute__((ext_vector_type(4)));
typedef float    f32x4 __attribute__((ext_vector_type(4)));

static constexpr size_t NX = (size_t)B * S * DM;   // 4,194,304
static constexpr size_t NW = (size_t)DM * DM;      // 1,048,576

// ---------------------------------------------------------------------------
// fp32 -> f16 conversion for x and the four weight matrices (one launch).
// ---------------------------------------------------------------------------
__global__ __launch_bounds__(256) void cvt_f16(const float* __restrict__ x,
                                               const float* __restrict__ wq,
                                               const float* __restrict__ wk,
                                               const float* __restrict__ wv,
                                               const float* __restrict__ wo,
                                               f16* __restrict__ xh,
                                               f16* __restrict__ wqh,
                                               f16* __restrict__ wkh,
                                               f16* __restrict__ wvh,
                                               f16* __restrict__ woh)
{
    const size_t base = ((size_t)blockIdx.x * 256 + threadIdx.x) * 8;
    const float* src; f16* dst; size_t off;
    if (base < NX) { src = x; dst = xh; off = base; }
    else {
        const size_t rem = base - NX;
        const int seg = (int)(rem >> 20);
        off = rem & (NW - 1);
        src = seg == 0 ? wq : (seg == 1 ? wk : (seg == 2 ? wv : wo));
        dst = seg == 0 ? wqh : (seg == 1 ? wkh : (seg == 2 ? wvh : woh));
    }
    float4 a = *(const float4*)&src[off];
    float4 b = *(const float4*)&src[off + 4];
    f16x8 h = { (f16)a.x, (f16)a.y, (f16)a.z, (f16)a.w,
                (f16)b.x, (f16)b.y, (f16)b.z, (f16)b.w };
    *(f16x8*)&dst[off] = h;
}

// ---------------------------------------------------------------------------
// f16 MFMA GEMM (round-4 structure: register prefetch of next tile overlaps
// MFMA compute; stride-72 LDS, <=2-way bank alias on all frag reads).
// NOTE: round-5's global_load_lds 2-barrier variant REGRESSED (+8us) — fetch
// sat un-overlapped between barriers with K only 1024. Keep this structure.
// ---------------------------------------------------------------------------
template<int MODE>
__global__ __launch_bounds__(256) void gemm_h(const f16* __restrict__ A,
                                              const f16* __restrict__ W0,
                                              const f16* __restrict__ W1,
                                              const f16* __restrict__ W2,
                                              const float* __restrict__ b0,
                                              const float* __restrict__ b1,
                                              const float* __restrict__ b2,
                                              void* __restrict__ o0,
                                              void* __restrict__ o1,
                                              void* __restrict__ o2)
{
    __shared__ f16 As[128 * 72];
    __shared__ f16 Bs[128 * 72];

    const int t    = threadIdx.x;
    const int w    = t >> 6;
    const int lane = t & 63;
    const int tx   = lane & 15;
    const int quad = lane >> 4;
    const int wm   = w >> 1;
    const int wn   = w & 1;
    const int m0   = blockIdx.y * 128;

    const f16* W; const float* bias; f16* outh = nullptr; float* outf = nullptr;
    float scale; int n0;
    if (MODE == 0) {
        const int wsel = blockIdx.x >> 3;
        n0   = (blockIdx.x & 7) * 128;
        W    = wsel == 0 ? W0 : (wsel == 1 ? W1 : W2);
        bias = wsel == 0 ? b0 : (wsel == 1 ? b1 : b2);
        outh = (f16*)(wsel == 0 ? o0 : (wsel == 1 ? o1 : o2));
        scale = wsel == 0 ? LOG2E * 0.125f : 1.0f;
    } else {
        n0 = blockIdx.x * 128;
        W = W0; bias = b0; outf = (float*)o0; scale = 1.0f;
    }

    const int lr = t >> 2;
    const int lc = (t & 3) * 8;

    f32x4 acc[4][4];
#pragma unroll
    for (int mt = 0; mt < 4; ++mt)
#pragma unroll
        for (int nt = 0; nt < 4; ++nt) acc[mt][nt] = (f32x4){0.f, 0.f, 0.f, 0.f};

    f16x8 ga[4], gb[4];
    {
        const f16* Ap = A + (size_t)(m0 + lr) * DM + lc;
        const f16* Wp = W + (size_t)(n0 + lr) * DM + lc;
        ga[0] = *(const f16x8*)(Ap);
        ga[1] = *(const f16x8*)(Ap + 32);
        ga[2] = *(const f16x8*)(Ap + (size_t)64 * DM);
        ga[3] = *(const f16x8*)(Ap + (size_t)64 * DM + 32);
        gb[0] = *(const f16x8*)(Wp);
        gb[1] = *(const f16x8*)(Wp + 32);
        gb[2] = *(const f16x8*)(Wp + (size_t)64 * DM);
        gb[3] = *(const f16x8*)(Wp + (size_t)64 * DM + 32);
    }

    for (int k0 = 0; k0 < DM; k0 += 64) {
        __syncthreads();
        *(f16x8*)&As[ lr       * 72 + lc     ] = ga[0];
        *(f16x8*)&As[ lr       * 72 + lc + 32] = ga[1];
        *(f16x8*)&As[(lr + 64) * 72 + lc     ] = ga[2];
        *(f16x8*)&As[(lr + 64) * 72 + lc + 32] = ga[3];
        *(f16x8*)&Bs[ lr       * 72 + lc     ] = gb[0];
        *(f16x8*)&Bs[ lr       * 72 + lc + 32] = gb[1];
        *(f16x8*)&Bs[(lr + 64) * 72 + lc     ] = gb[2];
        *(f16x8*)&Bs[(lr + 64) * 72 + lc + 32] = gb[3];
        if (k0 + 64 < DM) {
            const f16* Ap = A + (size_t)(m0 + lr) * DM + k0 + 64 + lc;
            const f16* Wp = W + (size_t)(n0 + lr) * DM + k0 + 64 + lc;
            ga[0] = *(const f16x8*)(Ap);
            ga[1] = *(const f16x8*)(Ap + 32);
            ga[2] = *(const f16x8*)(Ap + (size_t)64 * DM);
            ga[3] = *(const f16x8*)(Ap + (size_t)64 * DM + 32);
            gb[0] = *(const f16x8*)(Wp);
            gb[1] = *(const f16x8*)(Wp + 32);
            gb[2] = *(const f16x8*)(Wp + (size_t)64 * DM);
            gb[3] = *(const f16x8*)(Wp + (size_t)64 * DM + 32);
        }
        __syncthreads();

        f16x8 af[4][2];
#pragma unroll
        for (int mt = 0; mt < 4; ++mt)
#pragma unroll
            for (int ks = 0; ks < 2; ++ks)
                af[mt][ks] = *(const f16x8*)&As[(wm*64 + mt*16 + tx)*72 + ks*32 + quad*8];
#pragma unroll
        for (int nt = 0; nt < 4; ++nt) {
#pragma unroll
            for (int ks = 0; ks < 2; ++ks) {
                f16x8 bf = *(const f16x8*)&Bs[(wn*64 + nt*16 + tx)*72 + ks*32 + quad*8];
#pragma unroll
                for (int mt = 0; mt < 4; ++mt)
                    acc[mt][nt] = __builtin_amdgcn_mfma_f32_16x16x32_f16(af[mt][ks], bf, acc[mt][nt], 0, 0, 0);
            }
        }
    }

#pragma unroll
    for (int nt = 0; nt < 4; ++nt) {
        const int n = n0 + wn*64 + nt*16 + tx;
        const float bn = bias[n];
#pragma unroll
        for (int mt = 0; mt < 4; ++mt)
#pragma unroll
            for (int r = 0; r < 4; ++r) {
                const int m = m0 + wm*64 + mt*16 + quad*4 + r;
                const float v = (acc[mt][nt][r] + bn) * scale;
                if (MODE == 0) {
                    const int bi = m >> 11;
                    const int ss = m & (S - 1);
                    const int h  = n >> 6;
                    const int dk = n & (DK - 1);
                    outh[((size_t)((bi*NH + h)*S + ss))*DK + dk] = (f16)v;
                } else {
                    outf[(size_t)m * DM + n] = v;
                }
            }
    }
}

// ---------------------------------------------------------------------------
// Flash attention v4: S^T trick + fixed-max softmax + 4-way seq split (2048
// blocks -> ~8 blocks/CU resident for latency hiding). Rel-bias folded into
// the MFMA C-initializer (saves the post-MFMA adds). Partial numerators f16.
// ---------------------------------------------------------------------------
__global__ __launch_bounds__(256, 4) void attn_v4(const f16* __restrict__ Q,
                                                  const f16* __restrict__ K,
                                                  const f16* __restrict__ V,
                                                  const float* __restrict__ relb,
                                                  f16* __restrict__ On,
                                                  float* __restrict__ lp)
{
    __shared__ f16 Ks[64*72];
    __shared__ f16 Vt[64*72];    // quad-grouped V^T: addr(d,s)=d*72+g(s)
    __shared__ float rb2[257];

    const int t    = threadIdx.x;
    const int w    = t >> 6;
    const int lane = t & 63;
    const int tx   = lane & 15;
    const int quad = lane >> 4;
    const int qt   = blockIdx.x >> 2;
    const int sp   = blockIdx.x & 3;
    const int h    = blockIdx.y;
    const int b    = blockIdx.z;
    const int q0   = qt * 128;

    const f16* Qb = Q + (size_t)((b*NH + h) * S) * DK;
    const f16* Kb = K + (size_t)((b*NH + h) * S) * DK;
    const f16* Vb = V + (size_t)((b*NH + h) * S) * DK;

    for (int i = t; i < 257; i += 256) rb2[i] = relb[h*257 + i] * LOG2E - FMAX;

    const int qrow = q0 + w*32 + tx;
    f16x8 qf[2][2];
#pragma unroll
    for (int qb = 0; qb < 2; ++qb)
#pragma unroll
        for (int ks = 0; ks < 2; ++ks)
            qf[qb][ks] = *(const f16x8*)(Qb + (size_t)(qrow + qb*16)*DK + ks*32 + quad*8);

    f32x4 oT[4][2];
    float lsum[2] = {0.f, 0.f};
#pragma unroll
    for (int d = 0; d < 4; ++d)
#pragma unroll
        for (int qb = 0; qb < 2; ++qb) oT[d][qb] = (f32x4){0.f, 0.f, 0.f, 0.f};

    const int kt0 = sp * (S / 64 / NSPLIT);      // 8 tiles per split
    for (int kt = kt0; kt < kt0 + S/64/NSPLIT; ++kt) {
        const int k0 = kt * 64;

        const int seq = t & 63, d0k = (t >> 6) * 16;
        f16x8 kr0 = *(const f16x8*)(Kb + (size_t)(k0 + seq)*DK + d0k);
        f16x8 kr1 = *(const f16x8*)(Kb + (size_t)(k0 + seq)*DK + d0k + 8);
        const int s2 = (t & 31) * 2, d0v = (t >> 5) * 8;
        f16x8 vr0 = *(const f16x8*)(Vb + (size_t)(k0 + s2    )*DK + d0v);
        f16x8 vr1 = *(const f16x8*)(Vb + (size_t)(k0 + s2 + 1)*DK + d0v);

        __syncthreads();
        *(f16x8*)&Ks[seq*72 + d0k    ] = kr0;
        *(f16x8*)&Ks[seq*72 + d0k + 8] = kr1;
        {   // V^T quad-grouped: g(s) = ((s>>2)&3)*16 + (s>>4)*4 + (s&3)
            const int g = ((s2 >> 2) & 3)*16 + (s2 >> 4)*4 + (s2 & 3);
            const unsigned short* u0 = (const unsigned short*)&vr0;
            const unsigned short* u1 = (const unsigned short*)&vr1;
#pragma unroll
            for (int j = 0; j < 8; ++j) {
                unsigned int pw = (unsigned int)u0[j] | ((unsigned int)u1[j] << 16);
                *(unsigned int*)&Vt[(d0v + j)*72 + g] = pw;
            }
        }
        __syncthreads();

        const bool farlo = (k0 - q0) >= 256;
        const bool farhi = (q0 - k0) >= 192;
        const float bconst = farlo ? rb2[0] : rb2[256];
        const int relbase = (q0 + w*32 + tx) - (k0 + quad*4);

        f16x4 pf[4][2];
#pragma unroll
        for (int sb = 0; sb < 4; ++sb) {
            // bias as MFMA C-initializer (saves post-MFMA adds)
            f32x4 sT[2];
            if (farlo | farhi) {
                sT[0] = (f32x4){bconst, bconst, bconst, bconst};
                sT[1] = sT[0];
            } else {
#pragma unroll
                for (int qb = 0; qb < 2; ++qb)
#pragma unroll
                    for (int r = 0; r < 4; ++r) {
                        int rel = relbase + qb*16 - sb*16 - r;
                        rel = rel < -128 ? -128 : (rel > 128 ? 128 : rel);
                        sT[qb][r] = rb2[rel + 128];
                    }
            }
#pragma unroll
            for (int ks = 0; ks < 2; ++ks) {
                f16x8 kf = *(const f16x8*)&Ks[(sb*16 + tx)*72 + ks*32 + quad*8];
#pragma unroll
                for (int qb = 0; qb < 2; ++qb)
                    sT[qb] = __builtin_amdgcn_mfma_f32_16x16x32_f16(kf, qf[qb][ks], sT[qb], 0, 0, 0);
            }
#pragma unroll
            for (int qb = 0; qb < 2; ++qb)
#pragma unroll
                for (int r = 0; r < 4; ++r) {
                    const float p = exp2f(sT[qb][r]);
                    lsum[qb] += p;
                    pf[sb][qb][r] = (f16)p;
                }
        }

#pragma unroll
        for (int d = 0; d < 4; ++d) {
#pragma unroll
            for (int sp2 = 0; sp2 < 2; ++sp2) {
                f16x8 vv = *(const f16x8*)&Vt[(d*16 + tx)*72 + quad*16 + sp2*8];
                f16x4 vlo = __builtin_shufflevector(vv, vv, 0, 1, 2, 3);
                f16x4 vhi = __builtin_shufflevector(vv, vv, 4, 5, 6, 7);
#pragma unroll
                for (int qb = 0; qb < 2; ++qb) {
                    oT[d][qb] = __builtin_amdgcn_mfma_f32_16x16x16f16(vlo, pf[sp2*2    ][qb], oT[d][qb], 0, 0, 0);
                    oT[d][qb] = __builtin_amdgcn_mfma_f32_16x16x16f16(vhi, pf[sp2*2 + 1][qb], oT[d][qb], 0, 0, 0);
                }
            }
        }
    }

    // ---- epilogue: f16 partial numerator + partial denominator ----
#pragma unroll
    for (int qb = 0; qb < 2; ++qb) {
        float l = lsum[qb];
        l += __shfl_xor(l, 16);
        l += __shfl_xor(l, 32);
        const int q = q0 + w*32 + qb*16 + tx;
        if (quad == 0)
            lp[(((size_t)sp*B + b)*NH + h)*S + q] = l;
#pragma unroll
        for (int d = 0; d < 4; ++d) {
            f16x4 hv = { (f16)oT[d][qb][0], (f16)oT[d][qb][1],
                         (f16)oT[d][qb][2], (f16)oT[d][qb][3] };
            *(f16x4*)&On[(size_t)sp*NX + ((size_t)(b*S + q))*DM + h*DK + d*16 + quad*4] = hv;
        }
    }
}

// ---------------------------------------------------------------------------
// Combine the four seq-splits: AOh = (sum On_sp) / (sum l_sp), f16 output.
// ---------------------------------------------------------------------------
__global__ __launch_bounds__(256) void combine(const f16* __restrict__ On,
                                               const float* __restrict__ lp,
                                               f16* __restrict__ AOh)
{
    const size_t i8 = ((size_t)blockIdx.x * 256 + threadIdx.x) * 8;
    const int token = (int)(i8 >> 10);
    const int c     = (int)(i8 & (DM - 1));
    const int b     = token >> 11;
    const int st    = token & (S - 1);
    const int h     = c >> 6;
    float l = 0.f;
#pragma unroll
    for (int sp = 0; sp < NSPLIT; ++sp)
        l += lp[(((size_t)sp*B + b)*NH + h)*S + st];
    const float inv = 1.0f / l;
    float acc[8];
#pragma unroll
    for (int j = 0; j < 8; ++j) acc[j] = 0.f;
#pragma unroll
    for (int sp = 0; sp < NSPLIT; ++sp) {
        f16x8 v = *(const f16x8*)&On[(size_t)sp*NX + i8];
#pragma unroll
        for (int j = 0; j < 8; ++j) acc[j] += (float)v[j];
    }
    f16x8 o;
#pragma unroll
    for (int j = 0; j < 8; ++j) o[j] = (f16)(acc[j] * inv);
    *(f16x8*)&AOh[i8] = o;
}

// ---------------------------------------------------------------------------
extern "C" void kernel_launch(void* const* d_in, const int* in_sizes, int n_in,
                              void* d_out, int out_size, void* d_ws, size_t ws_size,
                              hipStream_t stream)
{
    const float* x    = (const float*)d_in[0];
    const float* Wq   = (const float*)d_in[1];
    const float* bq   = (const float*)d_in[2];
    const float* Wk   = (const float*)d_in[3];
    const float* bk   = (const float*)d_in[4];
    const float* Wv   = (const float*)d_in[5];
    const float* bv   = (const float*)d_in[6];
    const float* Wo   = (const float*)d_in[7];
    const float* bo   = (const float*)d_in[8];
    const float* relb = (const float*)d_in[9];

    f16* Xh  = (f16*)d_ws;
    f16* Wqh = Xh  + NX;
    f16* Wkh = Wqh + NW;
    f16* Wvh = Wkh + NW;
    f16* Woh = Wvh + NW;
    f16* Qh  = Woh + NW;
    f16* Kh  = Qh  + NX;
    f16* Vh  = Kh  + NX;
    f16* AOh = Vh  + NX;
    f16* On  = AOh + NX;                        // NSPLIT*NX halves
    float* lpart = (float*)(On + (size_t)NSPLIT*NX);  // NSPLIT*B*NH*S floats

    cvt_f16<<<(NX + 4*NW) / (256*8), 256, 0, stream>>>(x, Wq, Wk, Wv, Wo,
                                                       Xh, Wqh, Wkh, Wvh, Woh);
    gemm_h<0><<<dim3(24, 32), 256, 0, stream>>>(Xh, Wqh, Wkh, Wvh,
                                                bq, bk, bv, Qh, Kh, Vh);
    attn_v4<<<dim3((S/128)*NSPLIT, NH, B), 256, 0, stream>>>(Qh, Kh, Vh, relb, On, lpart);
    combine<<<NX / (256*8), 256, 0, stream>>>(On, lpart, AOh);
    gemm_h<1><<<dim3(8, 32), 256, 0, stream>>>(AOh, Woh, nullptr, nullptr,
                                               bo, nullptr, nullptr,
                                               d_out, nullptr, nullptr);
}